// Round 11
// baseline (308.704 us; speedup 1.0000x reference)
//
#include <hip/hip_runtime.h>
#include <cstdint>
#include <cstddef>

// Problem constants
#define DM 1024   // d_model
#define NH 16     // heads
#define DH 64     // d_head
#define NB 2      // batch
#define SQ 2048   // seq len
#define MT (NB*SQ) // 4096 total rows

typedef float  f32x4  __attribute__((ext_vector_type(4)));
typedef float  f32x16 __attribute__((ext_vector_type(16)));
typedef short  s16x8 __attribute__((ext_vector_type(8)));
typedef short  s16x4 __attribute__((ext_vector_type(4)));

// fp32 -> bf16 bits, round-to-nearest-even (no __hip_bfloat16 dependency)
__device__ __forceinline__ unsigned short f2bf(float x) {
    unsigned int u = __float_as_uint(x);
    unsigned int lsb = (u >> 16) & 1u;
    u += 0x7fffu + lsb;
    return (unsigned short)(u >> 16);
}

__device__ __forceinline__ float bf2f(unsigned short u) {
    return __uint_as_float(((unsigned int)u) << 16);
}

// packed fp32->bf16x2 (RNE), dst.lo16 = bf16(lo), dst.hi16 = bf16(hi)
__device__ __forceinline__ unsigned int cvtpk(float lo, float hi) {
    unsigned int r;
    asm("v_cvt_pk_bf16_f32 %0, %1, %2" : "=v"(r) : "v"(lo), "v"(hi));
    return r;
}

// async global->LDS, 16 bytes per lane (dest = wave-uniform base + lane*16)
__device__ __forceinline__ void gload16(const void* g, void* l) {
    __builtin_amdgcn_global_load_lds(
        (const __attribute__((address_space(1))) void*)g,
        (__attribute__((address_space(3))) void*)l,
        16, 0, 0);
}

// ---------------- merged cast kernel: all 7 fp32->bf16 tensors in one launch ----------------
#define BIGB (MT*DM/1024)   // 4096 blocks per activation tensor
#define WB_B (DM*DM/1024)   // 1024 blocks per weight tensor
__global__ __launch_bounds__(256) void castall(
    const float* __restrict__ s0, const float* __restrict__ s1, const float* __restrict__ s2,
    const float* __restrict__ s3, const float* __restrict__ s4, const float* __restrict__ s5,
    const float* __restrict__ s6,
    unsigned short* __restrict__ d0, unsigned short* __restrict__ d1,
    unsigned short* __restrict__ d2, unsigned short* __restrict__ d3,
    unsigned short* __restrict__ d4, unsigned short* __restrict__ d5,
    unsigned short* __restrict__ d6) {
    int bid = blockIdx.x;
    const float* src;
    unsigned short* dst;
    int off;
    if (bid < 3 * BIGB) {
        int seg = bid / BIGB;
        off = (bid - seg * BIGB) * 1024;
        src = (seg == 0) ? s0 : (seg == 1) ? s1 : s2;
        dst = (seg == 0) ? d0 : (seg == 1) ? d1 : d2;
    } else {
        int r = bid - 3 * BIGB;
        int seg = r / WB_B;
        off = (r - seg * WB_B) * 1024;
        src = (seg == 0) ? s3 : (seg == 1) ? s4 : (seg == 2) ? s5 : s6;
        dst = (seg == 0) ? d3 : (seg == 1) ? d4 : (seg == 2) ? d5 : d6;
    }
    int i = off + threadIdx.x * 4;
    float4 a = *reinterpret_cast<const float4*>(src + i);
    s16x4 rr;
    rr[0] = (short)f2bf(a.x);
    rr[1] = (short)f2bf(a.y);
    rr[2] = (short)f2bf(a.z);
    rr[3] = (short)f2bf(a.w);
    *reinterpret_cast<s16x4*>(dst + i) = rr;
}

// ---------------- GEMM core: C[m,n] = sum_k A[m,k]*B[n,k], 128x128 tile, BK=64 ----------------
__device__ __forceinline__ void gemm_core(const unsigned short* __restrict__ A,
                                          const unsigned short* __restrict__ Bm,
                                          int m0, int n0, int t,
                                          unsigned short (*As)[64],
                                          unsigned short (*Bs)[64],
                                          f32x4 acc[4][4]) {
    const int lane = t & 63, w = t >> 6;
    const int wm = (w >> 1) * 64, wn = (w & 1) * 64;
    const int lo = lane & 15, hi = lane >> 4;

    for (int k0 = 0; k0 < DM; k0 += 64) {
#pragma unroll
        for (int i = 0; i < 4; i++) {
            int c = i * 256 + t;
            int r = c >> 3, col = (c & 7) * 8;
            gload16(A  + (size_t)(m0 + r) * DM + k0 + col, &As[r][col]);
            gload16(Bm + (size_t)(n0 + r) * DM + k0 + col, &Bs[r][col]);
        }
        asm volatile("s_waitcnt vmcnt(0)" ::: "memory");
        __syncthreads();

#pragma unroll
        for (int kk = 0; kk < 64; kk += 32) {
            s16x8 a[4], b[4];
#pragma unroll
            for (int mi = 0; mi < 4; mi++)
                a[mi] = *reinterpret_cast<const s16x8*>(&As[wm + mi * 16 + lo][kk + hi * 8]);
#pragma unroll
            for (int ni = 0; ni < 4; ni++)
                b[ni] = *reinterpret_cast<const s16x8*>(&Bs[wn + ni * 16 + lo][kk + hi * 8]);
#pragma unroll
            for (int mi = 0; mi < 4; mi++)
#pragma unroll
                for (int ni = 0; ni < 4; ni++)
                    acc[mi][ni] = __builtin_amdgcn_mfma_f32_16x16x32_bf16(
                        a[mi], b[ni], acc[mi][ni], 0, 0, 0);
        }
        __syncthreads();
    }
}

// ---------------- fused QKV projection: z selects {q,k,v} ----------------
__global__ __launch_bounds__(256, 3) void gemm_qkv(
    const unsigned short* __restrict__ Qb, const unsigned short* __restrict__ Kb,
    const unsigned short* __restrict__ Vb,
    const unsigned short* __restrict__ Wq, const unsigned short* __restrict__ Wk,
    const unsigned short* __restrict__ Wv,
    const float* __restrict__ bq, const float* __restrict__ bk, const float* __restrict__ bv,
    unsigned short* __restrict__ qp, unsigned short* __restrict__ kp,
    unsigned short* __restrict__ vt) {
    __shared__ __align__(16) unsigned short As[128][64];
    __shared__ __align__(16) unsigned short Bs[128][64];
    const int t = threadIdx.x;
    const int z = blockIdx.z;
    const unsigned short* A    = (z == 0) ? Qb : (z == 1) ? Kb : Vb;
    const unsigned short* Bm   = (z == 0) ? Wq : (z == 1) ? Wk : Wv;
    const float*          bias = (z == 0) ? bq : (z == 1) ? bk : bv;
    const int m0 = blockIdx.y * 128, n0 = blockIdx.x * 128;

    f32x4 acc[4][4] = {};
    gemm_core(A, Bm, m0, n0, t, As, Bs, acc);

    const int lane = t & 63, w = t >> 6;
    const int wm = (w >> 1) * 64, wn = (w & 1) * 64;
    const int lo = lane & 15, hi = lane >> 4;

    if (z < 2) {
        unsigned short* C = z ? kp : qp;
        // q-scale: 1/sqrt(64) * log2(e) so attention scores are in the exp2 domain
        const float scale = z ? 1.0f : 0.18033688011112042f;
#pragma unroll
        for (int mi = 0; mi < 4; mi++)
#pragma unroll
            for (int ni = 0; ni < 4; ni++) {
                int cc = n0 + wn + ni * 16 + lo;
                float bb = bias[cc];
#pragma unroll
                for (int j = 0; j < 4; j++) {
                    int rr = m0 + wm + mi * 16 + hi * 4 + j;
                    C[(size_t)rr * DM + cc] = f2bf((acc[mi][ni][j] + bb) * scale);
                }
            }
    } else {
#pragma unroll
        for (int mi = 0; mi < 4; mi++)
#pragma unroll
            for (int ni = 0; ni < 4; ni++) {
                int cc = n0 + wn + ni * 16 + lo;       // 0..1023 = head*64 + d
                float bb = bias[cc];
                int rr0 = m0 + wm + mi * 16 + hi * 4;  // 4-aligned; tile never straddles b
                size_t base = ((size_t)(rr0 >> 11) * DM + cc) * SQ + (rr0 & (SQ - 1));
                s16x4 st;
#pragma unroll
                for (int j = 0; j < 4; j++)
                    st[j] = (short)f2bf(acc[mi][ni][j] + bb);
                *reinterpret_cast<s16x4*>(&vt[base]) = st;
            }
    }
}

// ---------------- final projection: fp32 out + bias ----------------
__global__ __launch_bounds__(256, 3) void gemm_out(
    const unsigned short* __restrict__ Ao, const unsigned short* __restrict__ Wo,
    const float* __restrict__ bo, float* __restrict__ Cout) {
    __shared__ __align__(16) unsigned short As[128][64];
    __shared__ __align__(16) unsigned short Bs[128][64];
    const int t = threadIdx.x;
    const int m0 = blockIdx.y * 128, n0 = blockIdx.x * 128;

    f32x4 acc[4][4] = {};
    gemm_core(Ao, Wo, m0, n0, t, As, Bs, acc);

    const int lane = t & 63, w = t >> 6;
    const int wm = (w >> 1) * 64, wn = (w & 1) * 64;
    const int lo = lane & 15, hi = lane >> 4;
#pragma unroll
    for (int mi = 0; mi < 4; mi++)
#pragma unroll
        for (int ni = 0; ni < 4; ni++) {
            int cc = n0 + wn + ni * 16 + lo;
            float bb = bo[cc];
#pragma unroll
            for (int j = 0; j < 4; j++) {
                int rr = m0 + wm + mi * 16 + hi * 4 + j;
                Cout[(size_t)rr * DM + cc] = acc[mi][ni][j] + bb;
            }
        }
}

// ---------------- flash attention, KV-split x2 (flash-decoding) ----------------
// grid = (SQ/128, NB*NH, 2); block = 256 (4 waves x 32 q-rows).
// Round-9 lesson: dbuf was null (wave-TLP already hides staging) -> reverted to
// single-buffer r8 structure. VALU is the 55%-busy pipe at only 2 waves/SIMD;
// KV-split doubles blocks/CU -> 4 waves/SIMD to saturate VALU.
// Each z-half covers kv in [z*1024, z*1024+1024); writes normalized partial O
// (bf16) + per-(row,head) (m, l) fp32; combine_k merges the two halves.
__global__ __launch_bounds__(256, 4) void attn_k(
    const unsigned short* __restrict__ qp, const unsigned short* __restrict__ kp,
    const unsigned short* __restrict__ vt,
    unsigned short* __restrict__ op, float* __restrict__ mlp) {
    __shared__ __align__(16) unsigned short Ks[128][64];   // swz ^(row&7)
    __shared__ __align__(16) unsigned short Vs[64][128];   // swz ^(row&15)

    const int t = threadIdx.x;
    const int lane = t & 63, w = t >> 6;
    const int l5 = lane & 31, hb = lane >> 5;
    const int q0 = blockIdx.x * 128;
    const int bh = blockIdx.y;         // b*16 + h
    const int b = bh >> 4, h = bh & 15;
    const int z = blockIdx.z;
    const int kt0 = z * (SQ / 2);

    // Q fragments straight from global (read once)
    const unsigned short* qrow = qp + (size_t)(b * SQ + q0 + w * 32 + l5) * DM + h * DH;
    s16x8 qfrag[4];
#pragma unroll
    for (int kk = 0; kk < 4; kk++)
        qfrag[kk] = *reinterpret_cast<const s16x8*>(qrow + kk * 16 + hb * 8);

    float mrow = -1e30f, lrow = 0.0f;
    f32x16 oaccT[2] = {};   // O^T frags: d = dblk*32+(reg&3)+8*(reg>>2)+4*hb, q = w*32+l5

    for (int ti = 0; ti < SQ / 256; ti++) {
        int kt = kt0 + ti * 128;
        // stage K tile (128x64) and V tile (64x128), source columns inverse-swizzled
#pragma unroll
        for (int i = 0; i < 4; i++) {
            int c = i * 256 + t;
            int r = c >> 3, col = ((c & 7) ^ (r & 7)) * 8;
            gload16(kp + (size_t)(b * SQ + kt + r) * DM + h * DH + col, &Ks[r][(c & 7) * 8]);
        }
#pragma unroll
        for (int i = 0; i < 4; i++) {
            int c = i * 256 + t;
            int r = c >> 4, col = ((c & 15) ^ (r & 15)) * 8;
            gload16(vt + (size_t)(bh * DH + r) * SQ + kt + col, &Vs[r][(c & 15) * 8]);
        }
        asm volatile("s_waitcnt vmcnt(0)" ::: "memory");
        __syncthreads();

        // S^T = K . Q^T : sT[ks] holds k-rows ks*32+(reg&3)+8*(reg>>2)+4*hb, q-col l5
        f32x16 sT[4] = {};
        __builtin_amdgcn_s_setprio(1);
#pragma unroll
        for (int ks = 0; ks < 4; ks++) {
#pragma unroll
            for (int kk = 0; kk < 4; kk++) {
                int kr = ks * 32 + l5;
                s16x8 kf = *reinterpret_cast<const s16x8*>(
                    &Ks[kr][((kk * 2 + hb) ^ (kr & 7)) * 8]);
                sT[ks] = __builtin_amdgcn_mfma_f32_32x32x16_bf16(
                    kf, qfrag[kk], sT[ks], 0, 0, 0);
            }
        }
        __builtin_amdgcn_s_setprio(0);

        // tile max via max3-shaped tree (v_max3_f32 fusion)
        float mx = -3.0e38f;
#pragma unroll
        for (int ks = 0; ks < 4; ks++) {
            float t0 = fmaxf(fmaxf(sT[ks][0], sT[ks][1]), sT[ks][2]);
            float t1 = fmaxf(fmaxf(sT[ks][3], sT[ks][4]), sT[ks][5]);
            float t2 = fmaxf(fmaxf(sT[ks][6], sT[ks][7]), sT[ks][8]);
            float t3 = fmaxf(fmaxf(sT[ks][9], sT[ks][10]), sT[ks][11]);
            float t4 = fmaxf(fmaxf(sT[ks][12], sT[ks][13]), sT[ks][14]);
            float t5 = fmaxf(fmaxf(sT[ks][15], t0), t1);
            float t6 = fmaxf(fmaxf(t2, t3), t4);
            mx = fmaxf(fmaxf(mx, t5), t6);
        }
        mx = fmaxf(mx, __shfl_xor(mx, 32));

        // defer-max (T13): only rescale when the tile max grew past THR=8 (exp2 dom)
        if (!__all(mx <= mrow + 8.0f)) {
            float mnew = fmaxf(mrow, mx);
            float fs = exp2f(mrow - mnew);
            mrow = mnew;
            lrow *= fs;
            oaccT[0] *= fs;
            oaccT[1] *= fs;
        }

        // P = exp2(S - mrow) (bounded by 2^8); multi-accumulator sum for ILP
        float ps0 = 0.0f, ps1 = 0.0f, ps2 = 0.0f, ps3 = 0.0f;
#pragma unroll
        for (int ks = 0; ks < 4; ks++)
#pragma unroll
            for (int r = 0; r < 16; r += 4) {
                float e0 = exp2f(sT[ks][r]     - mrow);
                float e1 = exp2f(sT[ks][r + 1] - mrow);
                float e2 = exp2f(sT[ks][r + 2] - mrow);
                float e3 = exp2f(sT[ks][r + 3] - mrow);
                sT[ks][r] = e0; sT[ks][r + 1] = e1;
                sT[ks][r + 2] = e2; sT[ks][r + 3] = e3;
                ps0 += e0; ps1 += e1; ps2 += e2; ps3 += e3;
            }
        float ps = (ps0 + ps1) + (ps2 + ps3);
        ps += __shfl_xor(ps, 32);
        lrow += ps;

        // PV: O^T += V^T . P^T, P packed via v_cvt_pk_bf16_f32 + lane^32 exchange
#pragma unroll
        for (int ks = 0; ks < 4; ks++) {
            unsigned int pw0[4], pw1[4];
#pragma unroll
            for (int m = 0; m < 4; m++) {
                pw0[m] = cvtpk(sT[ks][4 * m], sT[ks][4 * m + 1]);
                pw1[m] = cvtpk(sT[ks][4 * m + 2], sT[ks][4 * m + 3]);
            }
#pragma unroll
            for (int tt = 0; tt < 2; tt++) {
                unsigned int s0 = hb ? pw0[2 * tt] : pw0[2 * tt + 1];
                unsigned int s1 = hb ? pw1[2 * tt] : pw1[2 * tt + 1];
                unsigned int r0 = __shfl_xor(s0, 32);
                unsigned int r1 = __shfl_xor(s1, 32);
                union { unsigned int u[4]; s16x8 v; } uu;
                if (hb == 0) { uu.u[0] = pw0[2 * tt]; uu.u[1] = pw1[2 * tt];
                               uu.u[2] = r0;          uu.u[3] = r1; }
                else         { uu.u[0] = r0;          uu.u[1] = r1;
                               uu.u[2] = pw0[2 * tt + 1]; uu.u[3] = pw1[2 * tt + 1]; }
                s16x8 pf = uu.v;
                __builtin_amdgcn_s_setprio(1);
#pragma unroll
                for (int dblk = 0; dblk < 2; dblk++) {
                    int vr = dblk * 32 + l5;
                    int sl = ((ks * 2 + tt) * 2 + hb) ^ (vr & 15);
                    s16x8 vf = *reinterpret_cast<const s16x8*>(&Vs[vr][sl * 8]);
                    oaccT[dblk] = __builtin_amdgcn_mfma_f32_32x32x16_bf16(
                        vf, pf, oaccT[dblk], 0, 0, 0);
                }
                __builtin_amdgcn_s_setprio(0);
            }
        }
        __syncthreads();
    }

    // epilogue: normalized partial O (bf16) + (m,l) per row/head
    int grow = b * SQ + q0 + w * 32 + l5;     // global row in [MT]
    float inv = 1.0f / lrow;
    size_t rowbase = (size_t)z * MT * DM + (size_t)grow * DM + h * DH;
#pragma unroll
    for (int dblk = 0; dblk < 2; dblk++)
#pragma unroll
        for (int g = 0; g < 4; g++) {
            unsigned int w0 = cvtpk(oaccT[dblk][4 * g] * inv, oaccT[dblk][4 * g + 1] * inv);
            unsigned int w1 = cvtpk(oaccT[dblk][4 * g + 2] * inv, oaccT[dblk][4 * g + 3] * inv);
            uint2 st = make_uint2(w0, w1);
            *reinterpret_cast<uint2*>(&op[rowbase + dblk * 32 + 8 * g + 4 * hb]) = st;
        }
    if (hb == 0) {
        size_t mi = ((size_t)z * MT + grow) * NH + h;
        mlp[mi * 2 + 0] = mrow;
        mlp[mi * 2 + 1] = lrow;
    }
}

// ---------------- combine the two KV-halves ----------------
// grid = MT blocks x 256 thr; thread t handles 4 d of one row.
__global__ __launch_bounds__(256) void combine_k(
    const unsigned short* __restrict__ op, const float* __restrict__ mlp,
    unsigned short* __restrict__ ao) {
    int row = blockIdx.x;
    int d0 = threadIdx.x * 4;
    int h = d0 >> 6;
    size_t mi1 = ((size_t)row) * NH + h;
    size_t mi2 = ((size_t)MT + row) * NH + h;
    float m1 = mlp[mi1 * 2], l1 = mlp[mi1 * 2 + 1];
    float m2 = mlp[mi2 * 2], l2 = mlp[mi2 * 2 + 1];
    float M = fmaxf(m1, m2);
    float w1 = l1 * exp2f(m1 - M), w2 = l2 * exp2f(m2 - M);
    float inv = 1.0f / (w1 + w2);
    w1 *= inv; w2 *= inv;
    size_t i1 = (size_t)row * DM + d0;
    s16x4 a = *reinterpret_cast<const s16x4*>(&op[i1]);
    s16x4 bb = *reinterpret_cast<const s16x4*>(&op[(size_t)MT * DM + i1]);
    unsigned int o0 = cvtpk(bf2f((unsigned short)a[0]) * w1 + bf2f((unsigned short)bb[0]) * w2,
                            bf2f((unsigned short)a[1]) * w1 + bf2f((unsigned short)bb[1]) * w2);
    unsigned int o1 = cvtpk(bf2f((unsigned short)a[2]) * w1 + bf2f((unsigned short)bb[2]) * w2,
                            bf2f((unsigned short)a[3]) * w1 + bf2f((unsigned short)bb[3]) * w2);
    *reinterpret_cast<uint2*>(&ao[i1]) = make_uint2(o0, o1);
}

extern "C" void kernel_launch(void* const* d_in, const int* in_sizes, int n_in,
                              void* d_out, int out_size, void* d_ws, size_t ws_size,
                              hipStream_t stream) {
    const float* Q  = (const float*)d_in[0];
    const float* K  = (const float*)d_in[1];
    const float* V  = (const float*)d_in[2];
    const float* Wq = (const float*)d_in[3];
    const float* bq = (const float*)d_in[4];
    const float* Wk = (const float*)d_in[5];
    const float* bk = (const float*)d_in[6];
    const float* Wv = (const float*)d_in[7];
    const float* bv = (const float*)d_in[8];
    const float* Wo = (const float*)d_in[9];
    const float* bo = (const float*)d_in[10];

    // workspace layout (all 256B-aligned); total = 64 MiB
    char* ws = (char*)d_ws;
    size_t off = 0;
    auto alloc = [&](size_t bytes) {
        void* p = ws + off;
        off += (bytes + 255) & ~(size_t)255;
        return p;
    };
    const size_t XB = (size_t)MT * DM * 2;  // 8 MiB (bf16 activation)
    const size_t WB = (size_t)DM * DM * 2;  // 2 MiB (bf16 weight)
    unsigned short* qb  = (unsigned short*)alloc(XB);
    unsigned short* kb  = (unsigned short*)alloc(XB);
    unsigned short* vb  = (unsigned short*)alloc(XB);
    unsigned short* wqb = (unsigned short*)alloc(WB);
    unsigned short* wkb = (unsigned short*)alloc(WB);
    unsigned short* wvb = (unsigned short*)alloc(WB);
    unsigned short* wob = (unsigned short*)alloc(WB);
    unsigned short* qp  = (unsigned short*)alloc(XB);
    unsigned short* kp  = (unsigned short*)alloc(XB);
    unsigned short* vtp = (unsigned short*)alloc(XB);
    unsigned short* ao  = (unsigned short*)alloc(XB);

    // attn partials REUSE the cast buffers (dead after gemm_qkv):
    // op = [2][MT][DM] bf16 (16 MiB) occupies qb+kb; mlp = [2][MT][NH][2] f32 (1 MiB) in vb
    unsigned short* op  = qb;
    float*          mlp = (float*)vb;

    // 1) all fp32->bf16 casts in one launch
    castall<<<dim3(3 * BIGB + 4 * WB_B), 256, 0, stream>>>(
        Q, K, V, Wq, Wk, Wv, Wo, qb, kb, vb, wqb, wkb, wvb, wob);

    // 2) fused QKV projections (z = 0/1/2 -> q/k/v)
    gemm_qkv<<<dim3(DM / 128, MT / 128, 3), 256, 0, stream>>>(
        qb, kb, vb, wqb, wkb, wvb, bq, bk, bv, qp, kp, vtp);

    // 3) flash attention, KV-split x2
    attn_k<<<dim3(SQ / 128, NB * NH, 2), 256, 0, stream>>>(qp, kp, vtp, op, mlp);

    // 3b) combine halves
    combine_k<<<dim3(MT), 256, 0, stream>>>(op, mlp, ao);

    // 4) output projection (fp32 out)
    gemm_out<<<dim3(DM / 128, MT / 128), 256, 0, stream>>>(ao, wob, bo, (float*)d_out);
}

// Round 14
// 259.101 us; speedup vs baseline: 1.1914x; 1.1914x over previous
//
#include <hip/hip_runtime.h>
#include <cstdint>
#include <cstddef>

// Problem constants
#define DM 1024   // d_model
#define NH 16     // heads
#define DH 64     // d_head
#define NB 2      // batch
#define SQ 2048   // seq len
#define MT (NB*SQ) // 4096 total rows

typedef float  f32x4  __attribute__((ext_vector_type(4)));
typedef float  f32x16 __attribute__((ext_vector_type(16)));
typedef short  s16x8 __attribute__((ext_vector_type(8)));
typedef short  s16x4 __attribute__((ext_vector_type(4)));

// fp32 -> bf16 bits, round-to-nearest-even (no __hip_bfloat16 dependency)
__device__ __forceinline__ unsigned short f2bf(float x) {
    unsigned int u = __float_as_uint(x);
    unsigned int lsb = (u >> 16) & 1u;
    u += 0x7fffu + lsb;
    return (unsigned short)(u >> 16);
}

__device__ __forceinline__ float bf2f(unsigned short u) {
    return __uint_as_float(((unsigned int)u) << 16);
}

// packed fp32->bf16x2 (RNE), dst.lo16 = bf16(lo), dst.hi16 = bf16(hi)
__device__ __forceinline__ unsigned int cvtpk(float lo, float hi) {
    unsigned int r;
    asm("v_cvt_pk_bf16_f32 %0, %1, %2" : "=v"(r) : "v"(lo), "v"(hi));
    return r;
}

// async global->LDS, 16 bytes per lane (dest = wave-uniform base + lane*16)
__device__ __forceinline__ void gload16(const void* g, void* l) {
    __builtin_amdgcn_global_load_lds(
        (const __attribute__((address_space(1))) void*)g,
        (__attribute__((address_space(3))) void*)l,
        16, 0, 0);
}

// ---------------- merged cast kernel: all 7 fp32->bf16 tensors in one launch ----------------
#define BIGB (MT*DM/1024)   // 4096 blocks per activation tensor
#define WB_B (DM*DM/1024)   // 1024 blocks per weight tensor
__global__ __launch_bounds__(256) void castall(
    const float* __restrict__ s0, const float* __restrict__ s1, const float* __restrict__ s2,
    const float* __restrict__ s3, const float* __restrict__ s4, const float* __restrict__ s5,
    const float* __restrict__ s6,
    unsigned short* __restrict__ d0, unsigned short* __restrict__ d1,
    unsigned short* __restrict__ d2, unsigned short* __restrict__ d3,
    unsigned short* __restrict__ d4, unsigned short* __restrict__ d5,
    unsigned short* __restrict__ d6) {
    int bid = blockIdx.x;
    const float* src;
    unsigned short* dst;
    int off;
    if (bid < 3 * BIGB) {
        int seg = bid / BIGB;
        off = (bid - seg * BIGB) * 1024;
        src = (seg == 0) ? s0 : (seg == 1) ? s1 : s2;
        dst = (seg == 0) ? d0 : (seg == 1) ? d1 : d2;
    } else {
        int r = bid - 3 * BIGB;
        int seg = r / WB_B;
        off = (r - seg * WB_B) * 1024;
        src = (seg == 0) ? s3 : (seg == 1) ? s4 : (seg == 2) ? s5 : s6;
        dst = (seg == 0) ? d3 : (seg == 1) ? d4 : (seg == 2) ? d5 : d6;
    }
    int i = off + threadIdx.x * 4;
    float4 a = *reinterpret_cast<const float4*>(src + i);
    s16x4 rr;
    rr[0] = (short)f2bf(a.x);
    rr[1] = (short)f2bf(a.y);
    rr[2] = (short)f2bf(a.z);
    rr[3] = (short)f2bf(a.w);
    *reinterpret_cast<s16x4*>(dst + i) = rr;
}

// ---------------- GEMM core: C[m,n] = sum_k A[m,k]*B[n,k], 128x128 tile, BK=64 ----------------
__device__ __forceinline__ void gemm_core(const unsigned short* __restrict__ A,
                                          const unsigned short* __restrict__ Bm,
                                          int m0, int n0, int t,
                                          unsigned short (*As)[64],
                                          unsigned short (*Bs)[64],
                                          f32x4 acc[4][4]) {
    const int lane = t & 63, w = t >> 6;
    const int wm = (w >> 1) * 64, wn = (w & 1) * 64;
    const int lo = lane & 15, hi = lane >> 4;

    for (int k0 = 0; k0 < DM; k0 += 64) {
#pragma unroll
        for (int i = 0; i < 4; i++) {
            int c = i * 256 + t;
            int r = c >> 3, col = (c & 7) * 8;
            gload16(A  + (size_t)(m0 + r) * DM + k0 + col, &As[r][col]);
            gload16(Bm + (size_t)(n0 + r) * DM + k0 + col, &Bs[r][col]);
        }
        asm volatile("s_waitcnt vmcnt(0)" ::: "memory");
        __syncthreads();

#pragma unroll
        for (int kk = 0; kk < 64; kk += 32) {
            s16x8 a[4], b[4];
#pragma unroll
            for (int mi = 0; mi < 4; mi++)
                a[mi] = *reinterpret_cast<const s16x8*>(&As[wm + mi * 16 + lo][kk + hi * 8]);
#pragma unroll
            for (int ni = 0; ni < 4; ni++)
                b[ni] = *reinterpret_cast<const s16x8*>(&Bs[wn + ni * 16 + lo][kk + hi * 8]);
#pragma unroll
            for (int mi = 0; mi < 4; mi++)
#pragma unroll
                for (int ni = 0; ni < 4; ni++)
                    acc[mi][ni] = __builtin_amdgcn_mfma_f32_16x16x32_bf16(
                        a[mi], b[ni], acc[mi][ni], 0, 0, 0);
        }
        __syncthreads();
    }
}

// ---------------- fused QKV projection: z selects {q,k,v} ----------------
__global__ __launch_bounds__(256, 3) void gemm_qkv(
    const unsigned short* __restrict__ Qb, const unsigned short* __restrict__ Kb,
    const unsigned short* __restrict__ Vb,
    const unsigned short* __restrict__ Wq, const unsigned short* __restrict__ Wk,
    const unsigned short* __restrict__ Wv,
    const float* __restrict__ bq, const float* __restrict__ bk, const float* __restrict__ bv,
    unsigned short* __restrict__ qp, unsigned short* __restrict__ kp,
    unsigned short* __restrict__ vt) {
    __shared__ __align__(16) unsigned short As[128][64];
    __shared__ __align__(16) unsigned short Bs[128][64];
    const int t = threadIdx.x;
    const int z = blockIdx.z;
    const unsigned short* A    = (z == 0) ? Qb : (z == 1) ? Kb : Vb;
    const unsigned short* Bm   = (z == 0) ? Wq : (z == 1) ? Wk : Wv;
    const float*          bias = (z == 0) ? bq : (z == 1) ? bk : bv;
    const int m0 = blockIdx.y * 128, n0 = blockIdx.x * 128;

    f32x4 acc[4][4] = {};
    gemm_core(A, Bm, m0, n0, t, As, Bs, acc);

    const int lane = t & 63, w = t >> 6;
    const int wm = (w >> 1) * 64, wn = (w & 1) * 64;
    const int lo = lane & 15, hi = lane >> 4;

    if (z < 2) {
        unsigned short* C = z ? kp : qp;
        // q-scale: 1/sqrt(64) * log2(e) so attention scores are in the exp2 domain
        const float scale = z ? 1.0f : 0.18033688011112042f;
#pragma unroll
        for (int mi = 0; mi < 4; mi++)
#pragma unroll
            for (int ni = 0; ni < 4; ni++) {
                int cc = n0 + wn + ni * 16 + lo;
                float bb = bias[cc];
#pragma unroll
                for (int j = 0; j < 4; j++) {
                    int rr = m0 + wm + mi * 16 + hi * 4 + j;
                    C[(size_t)rr * DM + cc] = f2bf((acc[mi][ni][j] + bb) * scale);
                }
            }
    } else {
#pragma unroll
        for (int mi = 0; mi < 4; mi++)
#pragma unroll
            for (int ni = 0; ni < 4; ni++) {
                int cc = n0 + wn + ni * 16 + lo;       // 0..1023 = head*64 + d
                float bb = bias[cc];
                int rr0 = m0 + wm + mi * 16 + hi * 4;  // 4-aligned; tile never straddles b
                size_t base = ((size_t)(rr0 >> 11) * DM + cc) * SQ + (rr0 & (SQ - 1));
                s16x4 st;
#pragma unroll
                for (int j = 0; j < 4; j++)
                    st[j] = (short)f2bf(acc[mi][ni][j] + bb);
                *reinterpret_cast<s16x4*>(&vt[base]) = st;
            }
    }
}

// ---------------- final projection: fp32 out + bias ----------------
__global__ __launch_bounds__(256, 3) void gemm_out(
    const unsigned short* __restrict__ Ao, const unsigned short* __restrict__ Wo,
    const float* __restrict__ bo, float* __restrict__ Cout) {
    __shared__ __align__(16) unsigned short As[128][64];
    __shared__ __align__(16) unsigned short Bs[128][64];
    const int t = threadIdx.x;
    const int m0 = blockIdx.y * 128, n0 = blockIdx.x * 128;

    f32x4 acc[4][4] = {};
    gemm_core(Ao, Wo, m0, n0, t, As, Bs, acc);

    const int lane = t & 63, w = t >> 6;
    const int wm = (w >> 1) * 64, wn = (w & 1) * 64;
    const int lo = lane & 15, hi = lane >> 4;
#pragma unroll
    for (int mi = 0; mi < 4; mi++)
#pragma unroll
        for (int ni = 0; ni < 4; ni++) {
            int cc = n0 + wn + ni * 16 + lo;
            float bb = bo[cc];
#pragma unroll
            for (int j = 0; j < 4; j++) {
                int rr = m0 + wm + mi * 16 + hi * 4 + j;
                Cout[(size_t)rr * DM + cc] = acc[mi][ni][j] + bb;
            }
        }
}

// ---------------- flash attention, KV-split x2 (flash-decoding) ----------------
// grid = (SQ/128, NB*NH, 2); block = 256 (4 waves x 32 q-rows).
// ROUND-11 LESSON: __launch_bounds__(256,4) made the allocator cap VGPR at 64 ->
// sT[4] (64 regs) spilled to scratch -> FETCH 70->245 MB, dur 84->134us.
// Fix: bounds (256,2) (allocator budget 256). Compiler uses ~104 VGPR (r8
// evidence); 104 <= 128 so HARDWARE still co-schedules 4 blocks/CU (16 waves/CU)
// with the 1024-block grid -- the occupancy the split wanted, without spills.
// Each z-half covers kv in [z*1024, z*1024+1024); writes normalized partial O
// (bf16) + per-(row,head) (m, l) fp32; combine_k merges the two halves.
__global__ __launch_bounds__(256, 2) void attn_k(
    const unsigned short* __restrict__ qp, const unsigned short* __restrict__ kp,
    const unsigned short* __restrict__ vt,
    unsigned short* __restrict__ op, float* __restrict__ mlp) {
    __shared__ __align__(16) unsigned short Ks[128][64];   // swz ^(row&7)
    __shared__ __align__(16) unsigned short Vs[64][128];   // swz ^(row&15)

    const int t = threadIdx.x;
    const int lane = t & 63, w = t >> 6;
    const int l5 = lane & 31, hb = lane >> 5;
    const int q0 = blockIdx.x * 128;
    const int bh = blockIdx.y;         // b*16 + h
    const int b = bh >> 4, h = bh & 15;
    const int z = blockIdx.z;
    const int kt0 = z * (SQ / 2);

    // Q fragments straight from global (read once)
    const unsigned short* qrow = qp + (size_t)(b * SQ + q0 + w * 32 + l5) * DM + h * DH;
    s16x8 qfrag[4];
#pragma unroll
    for (int kk = 0; kk < 4; kk++)
        qfrag[kk] = *reinterpret_cast<const s16x8*>(qrow + kk * 16 + hb * 8);

    float mrow = -1e30f, lrow = 0.0f;
    f32x16 oaccT[2] = {};   // O^T frags: d = dblk*32+(reg&3)+8*(reg>>2)+4*hb, q = w*32+l5

    for (int ti = 0; ti < SQ / 256; ti++) {
        int kt = kt0 + ti * 128;
        // stage K tile (128x64) and V tile (64x128), source columns inverse-swizzled
#pragma unroll
        for (int i = 0; i < 4; i++) {
            int c = i * 256 + t;
            int r = c >> 3, col = ((c & 7) ^ (r & 7)) * 8;
            gload16(kp + (size_t)(b * SQ + kt + r) * DM + h * DH + col, &Ks[r][(c & 7) * 8]);
        }
#pragma unroll
        for (int i = 0; i < 4; i++) {
            int c = i * 256 + t;
            int r = c >> 4, col = ((c & 15) ^ (r & 15)) * 8;
            gload16(vt + (size_t)(bh * DH + r) * SQ + kt + col, &Vs[r][(c & 15) * 8]);
        }
        asm volatile("s_waitcnt vmcnt(0)" ::: "memory");
        __syncthreads();

        // S^T = K . Q^T : sT[ks] holds k-rows ks*32+(reg&3)+8*(reg>>2)+4*hb, q-col l5
        f32x16 sT[4] = {};
        __builtin_amdgcn_s_setprio(1);
#pragma unroll
        for (int ks = 0; ks < 4; ks++) {
#pragma unroll
            for (int kk = 0; kk < 4; kk++) {
                int kr = ks * 32 + l5;
                s16x8 kf = *reinterpret_cast<const s16x8*>(
                    &Ks[kr][((kk * 2 + hb) ^ (kr & 7)) * 8]);
                sT[ks] = __builtin_amdgcn_mfma_f32_32x32x16_bf16(
                    kf, qfrag[kk], sT[ks], 0, 0, 0);
            }
        }
        __builtin_amdgcn_s_setprio(0);

        // tile max via max3-shaped tree (v_max3_f32 fusion)
        float mx = -3.0e38f;
#pragma unroll
        for (int ks = 0; ks < 4; ks++) {
            float t0 = fmaxf(fmaxf(sT[ks][0], sT[ks][1]), sT[ks][2]);
            float t1 = fmaxf(fmaxf(sT[ks][3], sT[ks][4]), sT[ks][5]);
            float t2 = fmaxf(fmaxf(sT[ks][6], sT[ks][7]), sT[ks][8]);
            float t3 = fmaxf(fmaxf(sT[ks][9], sT[ks][10]), sT[ks][11]);
            float t4 = fmaxf(fmaxf(sT[ks][12], sT[ks][13]), sT[ks][14]);
            float t5 = fmaxf(fmaxf(sT[ks][15], t0), t1);
            float t6 = fmaxf(fmaxf(t2, t3), t4);
            mx = fmaxf(fmaxf(mx, t5), t6);
        }
        mx = fmaxf(mx, __shfl_xor(mx, 32));

        // defer-max (T13): only rescale when the tile max grew past THR=8 (exp2 dom)
        if (!__all(mx <= mrow + 8.0f)) {
            float mnew = fmaxf(mrow, mx);
            float fs = exp2f(mrow - mnew);
            mrow = mnew;
            lrow *= fs;
            oaccT[0] *= fs;
            oaccT[1] *= fs;
        }

        // P = exp2(S - mrow) (bounded by 2^8); multi-accumulator sum for ILP
        float ps0 = 0.0f, ps1 = 0.0f, ps2 = 0.0f, ps3 = 0.0f;
#pragma unroll
        for (int ks = 0; ks < 4; ks++)
#pragma unroll
            for (int r = 0; r < 16; r += 4) {
                float e0 = exp2f(sT[ks][r]     - mrow);
                float e1 = exp2f(sT[ks][r + 1] - mrow);
                float e2 = exp2f(sT[ks][r + 2] - mrow);
                float e3 = exp2f(sT[ks][r + 3] - mrow);
                sT[ks][r] = e0; sT[ks][r + 1] = e1;
                sT[ks][r + 2] = e2; sT[ks][r + 3] = e3;
                ps0 += e0; ps1 += e1; ps2 += e2; ps3 += e3;
            }
        float ps = (ps0 + ps1) + (ps2 + ps3);
        ps += __shfl_xor(ps, 32);
        lrow += ps;

        // PV: O^T += V^T . P^T, P packed via v_cvt_pk_bf16_f32 + lane^32 exchange
#pragma unroll
        for (int ks = 0; ks < 4; ks++) {
            unsigned int pw0[4], pw1[4];
#pragma unroll
            for (int m = 0; m < 4; m++) {
                pw0[m] = cvtpk(sT[ks][4 * m], sT[ks][4 * m + 1]);
                pw1[m] = cvtpk(sT[ks][4 * m + 2], sT[ks][4 * m + 3]);
            }
#pragma unroll
            for (int tt = 0; tt < 2; tt++) {
                unsigned int s0 = hb ? pw0[2 * tt] : pw0[2 * tt + 1];
                unsigned int s1 = hb ? pw1[2 * tt] : pw1[2 * tt + 1];
                unsigned int r0 = __shfl_xor(s0, 32);
                unsigned int r1 = __shfl_xor(s1, 32);
                union { unsigned int u[4]; s16x8 v; } uu;
                if (hb == 0) { uu.u[0] = pw0[2 * tt]; uu.u[1] = pw1[2 * tt];
                               uu.u[2] = r0;          uu.u[3] = r1; }
                else         { uu.u[0] = r0;          uu.u[1] = r1;
                               uu.u[2] = pw0[2 * tt + 1]; uu.u[3] = pw1[2 * tt + 1]; }
                s16x8 pf = uu.v;
                __builtin_amdgcn_s_setprio(1);
#pragma unroll
                for (int dblk = 0; dblk < 2; dblk++) {
                    int vr = dblk * 32 + l5;
                    int sl = ((ks * 2 + tt) * 2 + hb) ^ (vr & 15);
                    s16x8 vf = *reinterpret_cast<const s16x8*>(&Vs[vr][sl * 8]);
                    oaccT[dblk] = __builtin_amdgcn_mfma_f32_32x32x16_bf16(
                        vf, pf, oaccT[dblk], 0, 0, 0);
                }
                __builtin_amdgcn_s_setprio(0);
            }
        }
        __syncthreads();
    }

    // epilogue: normalized partial O (bf16) + (m,l) per row/head
    int grow = b * SQ + q0 + w * 32 + l5;     // global row in [MT]
    float inv = 1.0f / lrow;
    size_t rowbase = (size_t)z * MT * DM + (size_t)grow * DM + h * DH;
#pragma unroll
    for (int dblk = 0; dblk < 2; dblk++)
#pragma unroll
        for (int g = 0; g < 4; g++) {
            unsigned int w0 = cvtpk(oaccT[dblk][4 * g] * inv, oaccT[dblk][4 * g + 1] * inv);
            unsigned int w1 = cvtpk(oaccT[dblk][4 * g + 2] * inv, oaccT[dblk][4 * g + 3] * inv);
            uint2 st = make_uint2(w0, w1);
            *reinterpret_cast<uint2*>(&op[rowbase + dblk * 32 + 8 * g + 4 * hb]) = st;
        }
    if (hb == 0) {
        size_t mi = ((size_t)z * MT + grow) * NH + h;
        mlp[mi * 2 + 0] = mrow;
        mlp[mi * 2 + 1] = lrow;
    }
}

// ---------------- combine the two KV-halves ----------------
// grid = MT blocks x 256 thr; thread t handles 4 d of one row.
__global__ __launch_bounds__(256) void combine_k(
    const unsigned short* __restrict__ op, const float* __restrict__ mlp,
    unsigned short* __restrict__ ao) {
    int row = blockIdx.x;
    int d0 = threadIdx.x * 4;
    int h = d0 >> 6;
    size_t mi1 = ((size_t)row) * NH + h;
    size_t mi2 = ((size_t)MT + row) * NH + h;
    float m1 = mlp[mi1 * 2], l1 = mlp[mi1 * 2 + 1];
    float m2 = mlp[mi2 * 2], l2 = mlp[mi2 * 2 + 1];
    float M = fmaxf(m1, m2);
    float w1 = l1 * exp2f(m1 - M), w2 = l2 * exp2f(m2 - M);
    float inv = 1.0f / (w1 + w2);
    w1 *= inv; w2 *= inv;
    size_t i1 = (size_t)row * DM + d0;
    s16x4 a = *reinterpret_cast<const s16x4*>(&op[i1]);
    s16x4 bb = *reinterpret_cast<const s16x4*>(&op[(size_t)MT * DM + i1]);
    unsigned int o0 = cvtpk(bf2f((unsigned short)a[0]) * w1 + bf2f((unsigned short)bb[0]) * w2,
                            bf2f((unsigned short)a[1]) * w1 + bf2f((unsigned short)bb[1]) * w2);
    unsigned int o1 = cvtpk(bf2f((unsigned short)a[2]) * w1 + bf2f((unsigned short)bb[2]) * w2,
                            bf2f((unsigned short)a[3]) * w1 + bf2f((unsigned short)bb[3]) * w2);
    *reinterpret_cast<uint2*>(&ao[i1]) = make_uint2(o0, o1);
}

extern "C" void kernel_launch(void* const* d_in, const int* in_sizes, int n_in,
                              void* d_out, int out_size, void* d_ws, size_t ws_size,
                              hipStream_t stream) {
    const float* Q  = (const float*)d_in[0];
    const float* K  = (const float*)d_in[1];
    const float* V  = (const float*)d_in[2];
    const float* Wq = (const float*)d_in[3];
    const float* bq = (const float*)d_in[4];
    const float* Wk = (const float*)d_in[5];
    const float* bk = (const float*)d_in[6];
    const float* Wv = (const float*)d_in[7];
    const float* bv = (const float*)d_in[8];
    const float* Wo = (const float*)d_in[9];
    const float* bo = (const float*)d_in[10];

    // workspace layout (all 256B-aligned); total = 64 MiB
    char* ws = (char*)d_ws;
    size_t off = 0;
    auto alloc = [&](size_t bytes) {
        void* p = ws + off;
        off += (bytes + 255) & ~(size_t)255;
        return p;
    };
    const size_t XB = (size_t)MT * DM * 2;  // 8 MiB (bf16 activation)
    const size_t WB = (size_t)DM * DM * 2;  // 2 MiB (bf16 weight)
    unsigned short* qb  = (unsigned short*)alloc(XB);
    unsigned short* kb  = (unsigned short*)alloc(XB);
    unsigned short* vb  = (unsigned short*)alloc(XB);
    unsigned short* wqb = (unsigned short*)alloc(WB);
    unsigned short* wkb = (unsigned short*)alloc(WB);
    unsigned short* wvb = (unsigned short*)alloc(WB);
    unsigned short* wob = (unsigned short*)alloc(WB);
    unsigned short* qp  = (unsigned short*)alloc(XB);
    unsigned short* kp  = (unsigned short*)alloc(XB);
    unsigned short* vtp = (unsigned short*)alloc(XB);
    unsigned short* ao  = (unsigned short*)alloc(XB);

    // attn partials REUSE the cast buffers (dead after gemm_qkv):
    // op = [2][MT][DM] bf16 (16 MiB) occupies qb+kb; mlp = [2][MT][NH][2] f32 (1 MiB) in vb
    unsigned short* op  = qb;
    float*          mlp = (float*)vb;

    // 1) all fp32->bf16 casts in one launch
    castall<<<dim3(3 * BIGB + 4 * WB_B), 256, 0, stream>>>(
        Q, K, V, Wq, Wk, Wv, Wo, qb, kb, vb, wqb, wkb, wvb, wob);

    // 2) fused QKV projections (z = 0/1/2 -> q/k/v)
    gemm_qkv<<<dim3(DM / 128, MT / 128, 3), 256, 0, stream>>>(
        qb, kb, vb, wqb, wkb, wvb, bq, bk, bv, qp, kp, vtp);

    // 3) flash attention, KV-split x2
    attn_k<<<dim3(SQ / 128, NB * NH, 2), 256, 0, stream>>>(qp, kp, vtp, op, mlp);

    // 3b) combine halves
    combine_k<<<dim3(MT), 256, 0, stream>>>(op, mlp, ao);

    // 4) output projection (fp32 out)
    gemm_out<<<dim3(DM / 128, MT / 128), 256, 0, stream>>>(ao, wob, bo, (float*)d_out);
}